// Round 1
// baseline (4057.677 us; speedup 1.0000x reference)
//
#include <hip/hip_runtime.h>

#define H 128
#define LN_EPS 1e-5f
#define ROWS 16

// ---------------------------------------------------------------------------
// Kernel 1: msgs[dst] += e[i]  (segment_sum over edge destination)
// One thread per (edge, float4-column): E*32 threads.
// ---------------------------------------------------------------------------
__global__ __launch_bounds__(256) void scatter_add_kernel(
    const float* __restrict__ e, const int* __restrict__ ei,
    float* __restrict__ msgs, int E)
{
    long long gid = (long long)blockIdx.x * blockDim.x + threadIdx.x;
    long long total = (long long)E * (H / 4);
    if (gid >= total) return;
    int i = (int)(gid >> 5);          // edge index (H/4 == 32)
    int q = (int)(gid & 31);          // float4 column
    int dst = ei[E + i];              // end index
    float4 v = reinterpret_cast<const float4*>(e + (long long)i * H)[q];
    float* m = msgs + (long long)dst * H + q * 4;
    atomicAdd(m + 0, v.x);
    atomicAdd(m + 1, v.y);
    atomicAdd(m + 2, v.z);
    atomicAdd(m + 3, v.w);
}

// ---------------------------------------------------------------------------
// Kernel 2: node MLP.  in = [x | msgs] (256) -> Linear -> LN -> SiLU -> Linear
// -> + x.   16 rows per block, 256 threads: thread = (col j, row-group rg).
// ---------------------------------------------------------------------------
__global__ __launch_bounds__(256) void node_mlp_kernel(
    const float* __restrict__ x, const float* __restrict__ msgs,
    const float* __restrict__ W1, const float* __restrict__ b1,
    const float* __restrict__ g1, const float* __restrict__ be1,
    const float* __restrict__ W2, const float* __restrict__ b2,
    float* __restrict__ x_out, int N)
{
    __shared__ float in_s[ROWS][2 * H];     // 16 KB
    __shared__ float a_s[ROWS][H + 1];      // ~8.3 KB (padded: LN-stat reads)
    __shared__ float mu_s[ROWS], rs_s[ROWS];

    const int tid = threadIdx.x;
    const int row0 = blockIdx.x * ROWS;

    // ---- stage [x | msgs] rows into LDS (float4, coalesced) ----
    for (int idx = tid; idx < ROWS * (2 * H / 4); idx += 256) {
        int r  = idx / (2 * H / 4);
        int c4 = idx % (2 * H / 4);
        int row = row0 + r;
        float4 v = make_float4(0.f, 0.f, 0.f, 0.f);
        if (row < N) {
            if (c4 < H / 4)
                v = reinterpret_cast<const float4*>(x + (long long)row * H)[c4];
            else
                v = reinterpret_cast<const float4*>(msgs + (long long)row * H)[c4 - H / 4];
        }
        reinterpret_cast<float4*>(&in_s[r][0])[c4] = v;
    }
    __syncthreads();

    const int j  = tid & (H - 1);
    const int rg = tid >> 7;               // 0 or 1
    const int RB = ROWS / 2;               // 8 rows per thread

    // ---- matmul 1: h = in @ W1 + b1 ----
    float acc[RB];
    float bias1 = b1[j];
    #pragma unroll
    for (int r = 0; r < RB; ++r) acc[r] = bias1;
    #pragma unroll 4
    for (int k = 0; k < 2 * H; ++k) {
        float w = W1[k * H + j];
        #pragma unroll
        for (int r = 0; r < RB; ++r) acc[r] += in_s[rg * RB + r][k] * w;
    }
    #pragma unroll
    for (int r = 0; r < RB; ++r) a_s[rg * RB + r][j] = acc[r];
    __syncthreads();

    // ---- LayerNorm statistics: 16 lanes per row ----
    {
        int g = tid >> 4;                  // row 0..15
        int l = tid & 15;
        float s = 0.f, sq = 0.f;
        #pragma unroll
        for (int t = 0; t < H / 16; ++t) {
            float v = a_s[g][l + 16 * t];
            s += v; sq += v * v;
        }
        #pragma unroll
        for (int m = 8; m >= 1; m >>= 1) {
            s  += __shfl_xor(s, m);
            sq += __shfl_xor(sq, m);
        }
        if (l == 0) {
            float mu  = s * (1.0f / H);
            float var = sq * (1.0f / H) - mu * mu;   // biased var (torch LN)
            mu_s[g] = mu;
            rs_s[g] = rsqrtf(var + LN_EPS);
        }
    }
    __syncthreads();

    // ---- LN scale/shift + SiLU, in place ----
    for (int idx = tid; idx < ROWS * H; idx += 256) {
        int r = idx >> 7, c = idx & (H - 1);
        float v = (a_s[r][c] - mu_s[r]) * rs_s[r] * g1[c] + be1[c];
        a_s[r][c] = v / (1.0f + __expf(-v));
    }
    __syncthreads();

    // ---- matmul 2 + residual ----
    float acc2[RB];
    float bias2 = b2[j];
    #pragma unroll
    for (int r = 0; r < RB; ++r) acc2[r] = bias2;
    #pragma unroll 4
    for (int k = 0; k < H; ++k) {
        float w = W2[k * H + j];
        #pragma unroll
        for (int r = 0; r < RB; ++r) acc2[r] += a_s[rg * RB + r][k] * w;
    }
    #pragma unroll
    for (int r = 0; r < RB; ++r) {
        int row = row0 + rg * RB + r;
        if (row < N)
            x_out[(long long)row * H + j] = acc2[r] + x[(long long)row * H + j];
    }
}

// ---------------------------------------------------------------------------
// Kernel 3: edge MLP. in = [x_out[start] | x_out[end] | e] (384) -> MLP -> + e
// ---------------------------------------------------------------------------
__global__ __launch_bounds__(256) void edge_mlp_kernel(
    const float* __restrict__ x_out, const float* __restrict__ e,
    const int* __restrict__ ei,
    const float* __restrict__ W1, const float* __restrict__ b1,
    const float* __restrict__ g1, const float* __restrict__ be1,
    const float* __restrict__ W2, const float* __restrict__ b2,
    float* __restrict__ e_out, int E)
{
    __shared__ float in_s[ROWS][3 * H];     // 24 KB
    __shared__ float a_s[ROWS][H + 1];      // ~8.3 KB
    __shared__ float mu_s[ROWS], rs_s[ROWS];
    __shared__ int   sidx[ROWS], eidx[ROWS];

    const int tid = threadIdx.x;
    const int row0 = blockIdx.x * ROWS;

    if (tid < ROWS) {
        int row = row0 + tid;
        sidx[tid] = (row < E) ? ei[row] : 0;
        eidx[tid] = (row < E) ? ei[E + row] : 0;
    }
    __syncthreads();

    // ---- stage [x_out[s] | x_out[d] | e] rows into LDS ----
    for (int idx = tid; idx < ROWS * (3 * H / 4); idx += 256) {
        int r  = idx / (3 * H / 4);
        int c4 = idx % (3 * H / 4);
        int row = row0 + r;
        float4 v = make_float4(0.f, 0.f, 0.f, 0.f);
        if (row < E) {
            if (c4 < H / 4)
                v = reinterpret_cast<const float4*>(x_out + (long long)sidx[r] * H)[c4];
            else if (c4 < 2 * (H / 4))
                v = reinterpret_cast<const float4*>(x_out + (long long)eidx[r] * H)[c4 - H / 4];
            else
                v = reinterpret_cast<const float4*>(e + (long long)row * H)[c4 - 2 * (H / 4)];
        }
        reinterpret_cast<float4*>(&in_s[r][0])[c4] = v;
    }
    __syncthreads();

    const int j  = tid & (H - 1);
    const int rg = tid >> 7;
    const int RB = ROWS / 2;

    float acc[RB];
    float bias1 = b1[j];
    #pragma unroll
    for (int r = 0; r < RB; ++r) acc[r] = bias1;
    #pragma unroll 4
    for (int k = 0; k < 3 * H; ++k) {
        float w = W1[k * H + j];
        #pragma unroll
        for (int r = 0; r < RB; ++r) acc[r] += in_s[rg * RB + r][k] * w;
    }
    #pragma unroll
    for (int r = 0; r < RB; ++r) a_s[rg * RB + r][j] = acc[r];
    __syncthreads();

    {
        int g = tid >> 4;
        int l = tid & 15;
        float s = 0.f, sq = 0.f;
        #pragma unroll
        for (int t = 0; t < H / 16; ++t) {
            float v = a_s[g][l + 16 * t];
            s += v; sq += v * v;
        }
        #pragma unroll
        for (int m = 8; m >= 1; m >>= 1) {
            s  += __shfl_xor(s, m);
            sq += __shfl_xor(sq, m);
        }
        if (l == 0) {
            float mu  = s * (1.0f / H);
            float var = sq * (1.0f / H) - mu * mu;
            mu_s[g] = mu;
            rs_s[g] = rsqrtf(var + LN_EPS);
        }
    }
    __syncthreads();

    for (int idx = tid; idx < ROWS * H; idx += 256) {
        int r = idx >> 7, c = idx & (H - 1);
        float v = (a_s[r][c] - mu_s[r]) * rs_s[r] * g1[c] + be1[c];
        a_s[r][c] = v / (1.0f + __expf(-v));
    }
    __syncthreads();

    float acc2[RB];
    float bias2 = b2[j];
    #pragma unroll
    for (int r = 0; r < RB; ++r) acc2[r] = bias2;
    #pragma unroll 4
    for (int k = 0; k < H; ++k) {
        float w = W2[k * H + j];
        #pragma unroll
        for (int r = 0; r < RB; ++r) acc2[r] += a_s[rg * RB + r][k] * w;
    }
    #pragma unroll
    for (int r = 0; r < RB; ++r) {
        int row = row0 + rg * RB + r;
        if (row < E)
            e_out[(long long)row * H + j] = acc2[r] + e[(long long)row * H + j];
    }
}

// ---------------------------------------------------------------------------
extern "C" void kernel_launch(void* const* d_in, const int* in_sizes, int n_in,
                              void* d_out, int out_size, void* d_ws, size_t ws_size,
                              hipStream_t stream)
{
    const float* x     = (const float*)d_in[0];
    const int*   ei    = (const int*)  d_in[1];
    const float* e     = (const float*)d_in[2];
    const float* Wn1   = (const float*)d_in[3];
    const float* bn1   = (const float*)d_in[4];
    const float* gn1   = (const float*)d_in[5];
    const float* betan1= (const float*)d_in[6];
    const float* Wn2   = (const float*)d_in[7];
    const float* bn2   = (const float*)d_in[8];
    const float* We1   = (const float*)d_in[9];
    const float* be1   = (const float*)d_in[10];
    const float* ge1   = (const float*)d_in[11];
    const float* betae1= (const float*)d_in[12];
    const float* We2   = (const float*)d_in[13];
    const float* be2   = (const float*)d_in[14];

    const int N = in_sizes[0] / H;
    const int E = in_sizes[2] / H;

    float* x_out = (float*)d_out;
    float* e_out = (float*)d_out + (long long)N * H;
    float* msgs  = (float*)d_ws;                 // N*H fp32 scratch

    hipMemsetAsync(msgs, 0, (size_t)N * H * sizeof(float), stream);

    {
        long long total = (long long)E * (H / 4);
        int blocks = (int)((total + 255) / 256);
        scatter_add_kernel<<<blocks, 256, 0, stream>>>(e, ei, msgs, E);
    }
    {
        int blocks = (N + ROWS - 1) / ROWS;
        node_mlp_kernel<<<blocks, 256, 0, stream>>>(
            x, msgs, Wn1, bn1, gn1, betan1, Wn2, bn2, x_out, N);
    }
    {
        int blocks = (E + ROWS - 1) / ROWS;
        edge_mlp_kernel<<<blocks, 256, 0, stream>>>(
            x_out, e, ei, We1, be1, ge1, betae1, We2, be2, e_out, E);
    }
}

// Round 2
// 2452.218 us; speedup vs baseline: 1.6547x; 1.6547x over previous
//
#include <hip/hip_runtime.h>

#define H 128
#define LN_EPS 1e-5f

typedef __attribute__((ext_vector_type(8))) short bf16x8;
typedef __attribute__((ext_vector_type(4))) float f32x4;

__device__ __forceinline__ ushort f2bf(float f) {
    unsigned u = __builtin_bit_cast(unsigned, f);
    u += 0x7fffu + ((u >> 16) & 1u);          // RNE
    return (ushort)(u >> 16);
}

__device__ __forceinline__ f32x4 mfma16(bf16x8 a, bf16x8 b, f32x4 c) {
    return __builtin_amdgcn_mfma_f32_16x16x32_bf16(a, b, c, 0, 0, 0);
}

// ---------------------------------------------------------------------------
// Kernel 1: msgs[dst] += e[i]  (segment_sum over edge destination)
// ---------------------------------------------------------------------------
__global__ __launch_bounds__(256) void scatter_add_kernel(
    const float* __restrict__ e, const int* __restrict__ ei,
    float* __restrict__ msgs, int E)
{
    long long gid = (long long)blockIdx.x * blockDim.x + threadIdx.x;
    long long total = (long long)E * (H / 4);
    if (gid >= total) return;
    int i = (int)(gid >> 5);
    int q = (int)(gid & 31);
    int dst = ei[E + i];
    float4 v = reinterpret_cast<const float4*>(e + (long long)i * H)[q];
    float* m = msgs + (long long)dst * H + q * 4;
    atomicAdd(m + 0, v.x);
    atomicAdd(m + 1, v.y);
    atomicAdd(m + 2, v.z);
    atomicAdd(m + 3, v.w);
}

// ---------------------------------------------------------------------------
// Weight prep: W[K][128] fp32  ->  Wt[128][K] bf16  (B-operand layout)
// ---------------------------------------------------------------------------
__global__ __launch_bounds__(256) void wtrans_kernel(
    const float* __restrict__ W, ushort* __restrict__ Wt, int K)
{
    int idx = blockIdx.x * 256 + threadIdx.x;
    if (idx >= K * H) return;
    int k = idx >> 7, n = idx & (H - 1);
    Wt[n * K + k] = f2bf(W[idx]);
}

// ---------------------------------------------------------------------------
// Fused MLP via MFMA: [stage inputs bf16] -> in@W1+b1 -> LN -> SiLU -> @W2+b2
// -> +res.  64 rows/block, 4 waves; wave w owns rows (w&1)*32..+32,
// cols (w>>1)*64..+64 of the output tile.
// MFMA 16x16x32 layouts: A row=lane&15,k=(lane>>4)*8+e ; B col=lane&15 same k;
// C/D col=lane&15, row=(lane>>4)*4+reg.
// ---------------------------------------------------------------------------
template<int K, bool GATHER>
__global__ __launch_bounds__(256) void mlp_mfma_kernel(
    const float* __restrict__ in0,   // GATHER: x_out (gather src) | node: x
    const float* __restrict__ in1,   // GATHER: e                  | node: msgs
    const int* __restrict__ ei,      // GATHER only
    const ushort* __restrict__ W1t,  // [128][K] bf16
    const float* __restrict__ b1,
    const float* __restrict__ g1, const float* __restrict__ be1,
    const ushort* __restrict__ W2t,  // [128][128] bf16
    const float* __restrict__ b2,
    const float* __restrict__ res,
    float* __restrict__ out, int M)
{
    constexpr int KP = K + 8;                 // +16B pad: banks shift 4/row
    __shared__ ushort in_s[64][KP];
    __shared__ ushort h_s[64][H + 8];
    __shared__ float part_s[2][64], part_q[2][64];
    __shared__ int sidx[64], eidx[64];

    const int tid = threadIdx.x;
    const int row0 = blockIdx.x * 64;

    if constexpr (GATHER) {
        if (tid < 64) {
            int row = row0 + tid;
            sidx[tid] = (row < M) ? ei[row] : 0;
            eidx[tid] = (row < M) ? ei[M + row] : 0;
        }
        __syncthreads();
    }

    // ---- stage input rows as bf16 into LDS ----
    constexpr int C4 = K / 4;
    for (int idx = tid; idx < 64 * C4; idx += 256) {
        int r = idx / C4, c4 = idx % C4;
        int row = row0 + r;
        float4 v = make_float4(0.f, 0.f, 0.f, 0.f);
        if (row < M) {
            if constexpr (GATHER) {
                if (c4 < H / 4)
                    v = reinterpret_cast<const float4*>(in0 + (long long)sidx[r] * H)[c4];
                else if (c4 < 2 * (H / 4))
                    v = reinterpret_cast<const float4*>(in0 + (long long)eidx[r] * H)[c4 - H / 4];
                else
                    v = reinterpret_cast<const float4*>(in1 + (long long)row * H)[c4 - 2 * (H / 4)];
            } else {
                if (c4 < H / 4)
                    v = reinterpret_cast<const float4*>(in0 + (long long)row * H)[c4];
                else
                    v = reinterpret_cast<const float4*>(in1 + (long long)row * H)[c4 - H / 4];
            }
        }
        ushort4 bv;
        bv.x = f2bf(v.x); bv.y = f2bf(v.y); bv.z = f2bf(v.z); bv.w = f2bf(v.w);
        *reinterpret_cast<ushort4*>(&in_s[r][c4 * 4]) = bv;
    }
    __syncthreads();

    const int lane = tid & 63;
    const int w    = tid >> 6;
    const int l15  = lane & 15;
    const int lg   = lane >> 4;               // 0..3
    const int mrow = (w & 1) * 32;
    const int ncol = (w >> 1) * 64;

    // ---- matmul 1 ----
    f32x4 acc[2][4];
    #pragma unroll
    for (int mt = 0; mt < 2; ++mt)
        #pragma unroll
        for (int nt = 0; nt < 4; ++nt)
            acc[mt][nt] = (f32x4){0.f, 0.f, 0.f, 0.f};

    #pragma unroll 2
    for (int ks = 0; ks < K / 32; ++ks) {
        int k0 = ks * 32 + lg * 8;
        bf16x8 a0 = *reinterpret_cast<const bf16x8*>(&in_s[mrow + l15][k0]);
        bf16x8 a1 = *reinterpret_cast<const bf16x8*>(&in_s[mrow + 16 + l15][k0]);
        #pragma unroll
        for (int nt = 0; nt < 4; ++nt) {
            bf16x8 bfr = *reinterpret_cast<const bf16x8*>(
                &W1t[(size_t)(ncol + nt * 16 + l15) * K + k0]);
            acc[0][nt] = mfma16(a0, bfr, acc[0][nt]);
            acc[1][nt] = mfma16(a1, bfr, acc[1][nt]);
        }
    }

    // ---- bias, LN statistics (in-register + cross-wave-pair via LDS) ----
    float b1c[4], g1c[4], be1c[4];
    #pragma unroll
    for (int nt = 0; nt < 4; ++nt) {
        int c = ncol + nt * 16 + l15;
        b1c[nt] = b1[c]; g1c[nt] = g1[c]; be1c[nt] = be1[c];
    }
    #pragma unroll
    for (int mt = 0; mt < 2; ++mt)
        #pragma unroll
        for (int nt = 0; nt < 4; ++nt)
            #pragma unroll
            for (int r = 0; r < 4; ++r)
                acc[mt][nt][r] += b1c[nt];

    #pragma unroll
    for (int mt = 0; mt < 2; ++mt) {
        #pragma unroll
        for (int r = 0; r < 4; ++r) {
            float s = acc[mt][0][r] + acc[mt][1][r] + acc[mt][2][r] + acc[mt][3][r];
            float q = acc[mt][0][r] * acc[mt][0][r] + acc[mt][1][r] * acc[mt][1][r]
                    + acc[mt][2][r] * acc[mt][2][r] + acc[mt][3][r] * acc[mt][3][r];
            #pragma unroll
            for (int m = 8; m >= 1; m >>= 1) {
                s += __shfl_xor(s, m);
                q += __shfl_xor(q, m);
            }
            if (l15 == 0) {
                int rl = mrow + mt * 16 + lg * 4 + r;
                part_s[w >> 1][rl] = s;
                part_q[w >> 1][rl] = q;
            }
        }
    }
    __syncthreads();

    // ---- LN apply + SiLU + write h (bf16) to LDS ----
    #pragma unroll
    for (int mt = 0; mt < 2; ++mt) {
        #pragma unroll
        for (int r = 0; r < 4; ++r) {
            int rl = mrow + mt * 16 + lg * 4 + r;
            float s  = part_s[0][rl] + part_s[1][rl];
            float q  = part_q[0][rl] + part_q[1][rl];
            float mu = s * (1.0f / H);
            float rs = rsqrtf(q * (1.0f / H) - mu * mu + LN_EPS);
            #pragma unroll
            for (int nt = 0; nt < 4; ++nt) {
                float v = (acc[mt][nt][r] - mu) * rs * g1c[nt] + be1c[nt];
                v = v / (1.0f + __expf(-v));
                h_s[rl][ncol + nt * 16 + l15] = f2bf(v);
            }
        }
    }
    __syncthreads();

    // ---- matmul 2 ----
    f32x4 acc2[2][4];
    #pragma unroll
    for (int nt = 0; nt < 4; ++nt) {
        float bb = b2[ncol + nt * 16 + l15];
        #pragma unroll
        for (int mt = 0; mt < 2; ++mt)
            acc2[mt][nt] = (f32x4){bb, bb, bb, bb};
    }
    #pragma unroll
    for (int ks = 0; ks < H / 32; ++ks) {
        int k0 = ks * 32 + lg * 8;
        bf16x8 a0 = *reinterpret_cast<const bf16x8*>(&h_s[mrow + l15][k0]);
        bf16x8 a1 = *reinterpret_cast<const bf16x8*>(&h_s[mrow + 16 + l15][k0]);
        #pragma unroll
        for (int nt = 0; nt < 4; ++nt) {
            bf16x8 bfr = *reinterpret_cast<const bf16x8*>(
                &W2t[(size_t)(ncol + nt * 16 + l15) * H + k0]);
            acc2[0][nt] = mfma16(a0, bfr, acc2[0][nt]);
            acc2[1][nt] = mfma16(a1, bfr, acc2[1][nt]);
        }
    }

    // ---- residual + store ----
    #pragma unroll
    for (int mt = 0; mt < 2; ++mt) {
        #pragma unroll
        for (int r = 0; r < 4; ++r) {
            int row = row0 + mrow + mt * 16 + lg * 4 + r;
            if (row < M) {
                const float* rp = res + (size_t)row * H;
                float* op = out + (size_t)row * H;
                #pragma unroll
                for (int nt = 0; nt < 4; ++nt) {
                    int c = ncol + nt * 16 + l15;
                    op[c] = acc2[mt][nt][r] + rp[c];
                }
            }
        }
    }
}

// ---------------------------------------------------------------------------
extern "C" void kernel_launch(void* const* d_in, const int* in_sizes, int n_in,
                              void* d_out, int out_size, void* d_ws, size_t ws_size,
                              hipStream_t stream)
{
    const float* x     = (const float*)d_in[0];
    const int*   ei    = (const int*)  d_in[1];
    const float* e     = (const float*)d_in[2];
    const float* Wn1   = (const float*)d_in[3];
    const float* bn1   = (const float*)d_in[4];
    const float* gn1   = (const float*)d_in[5];
    const float* betan1= (const float*)d_in[6];
    const float* Wn2   = (const float*)d_in[7];
    const float* bn2   = (const float*)d_in[8];
    const float* We1   = (const float*)d_in[9];
    const float* be1   = (const float*)d_in[10];
    const float* ge1   = (const float*)d_in[11];
    const float* betae1= (const float*)d_in[12];
    const float* We2   = (const float*)d_in[13];
    const float* be2   = (const float*)d_in[14];

    const int N = in_sizes[0] / H;
    const int E = in_sizes[2] / H;

    float* x_out = (float*)d_out;
    float* e_out = (float*)d_out + (long long)N * H;

    float*  msgs = (float*)d_ws;                       // N*H fp32
    ushort* Wn1t = (ushort*)(msgs + (size_t)N * H);    // [128][256]
    ushort* Wn2t = Wn1t + 256 * H;                     // [128][128]
    ushort* We1t = Wn2t + H * H;                       // [128][384]
    ushort* We2t = We1t + 384 * H;                     // [128][128]

    hipMemsetAsync(msgs, 0, (size_t)N * H * sizeof(float), stream);

    wtrans_kernel<<<(256 * H + 255) / 256, 256, 0, stream>>>(Wn1, Wn1t, 256);
    wtrans_kernel<<<(H * H + 255) / 256, 256, 0, stream>>>(Wn2, Wn2t, H);
    wtrans_kernel<<<(384 * H + 255) / 256, 256, 0, stream>>>(We1, We1t, 384);
    wtrans_kernel<<<(H * H + 255) / 256, 256, 0, stream>>>(We2, We2t, H);

    {
        long long total = (long long)E * (H / 4);
        int blocks = (int)((total + 255) / 256);
        scatter_add_kernel<<<blocks, 256, 0, stream>>>(e, ei, msgs, E);
    }
    {
        int blocks = (N + 63) / 64;
        mlp_mfma_kernel<256, false><<<blocks, 256, 0, stream>>>(
            x, msgs, nullptr, Wn1t, bn1, gn1, betan1, Wn2t, bn2, x, x_out, N);
    }
    {
        int blocks = (E + 63) / 64;
        mlp_mfma_kernel<384, true><<<blocks, 256, 0, stream>>>(
            x_out, e, ei, We1t, be1, ge1, betae1, We2t, be2, e, e_out, E);
    }
}

// Round 3
// 1351.736 us; speedup vs baseline: 3.0018x; 1.8141x over previous
//
#include <hip/hip_runtime.h>

#define H 128
#define LN_EPS 1e-5f

typedef __attribute__((ext_vector_type(8))) short bf16x8;
typedef __attribute__((ext_vector_type(4))) float f32x4;

__device__ __forceinline__ ushort f2bf(float f) {
    unsigned u = __builtin_bit_cast(unsigned, f);
    u += 0x7fffu + ((u >> 16) & 1u);          // RNE
    return (ushort)(u >> 16);
}

__device__ __forceinline__ f32x4 mfma16(bf16x8 a, bf16x8 b, f32x4 c) {
    return __builtin_amdgcn_mfma_f32_16x16x32_bf16(a, b, c, 0, 0, 0);
}

// ---------------------------------------------------------------------------
// Scatter replacement: counting-sort by destination, then gather-sum.
// ---------------------------------------------------------------------------
__global__ __launch_bounds__(256) void hist_kernel(
    const int* __restrict__ ei, int* __restrict__ cnt, int E)
{
    int i = blockIdx.x * 256 + threadIdx.x;
    if (i < E) atomicAdd(&cnt[ei[E + i]], 1);
}

// single-block exclusive scan over cnt[0..N) -> off[0..N]
__global__ __launch_bounds__(1024) void scan_kernel(
    const int* __restrict__ cnt, int* __restrict__ off, int N)
{
    __shared__ int s[1024];
    const int t = threadIdx.x;
    const int chunk = (N + 1023) / 1024;
    const int lo = t * chunk, hi = min(lo + chunk, N);
    int sum = 0;
    for (int i = lo; i < hi; ++i) sum += cnt[i];
    s[t] = sum;
    __syncthreads();
    // inclusive Hillis-Steele
    for (int d = 1; d < 1024; d <<= 1) {
        int v = (t >= d) ? s[t - d] : 0;
        __syncthreads();
        s[t] += v;
        __syncthreads();
    }
    int running = s[t] - sum;                 // exclusive base
    for (int i = lo; i < hi; ++i) {
        off[i] = running;
        running += cnt[i];
    }
    if (t == 1023) off[N] = running;
}

__global__ __launch_bounds__(256) void reorder_kernel(
    const int* __restrict__ ei, int* __restrict__ cursor,
    int* __restrict__ sorted, int E)
{
    int i = blockIdx.x * 256 + threadIdx.x;
    if (i < E) {
        int pos = atomicAdd(&cursor[ei[E + i]], 1);
        sorted[pos] = i;
    }
}

// one wave per node: sum e[eid] rows for eid in sorted[off[n]..off[n+1])
__global__ __launch_bounds__(256) void segsum_kernel(
    const float* __restrict__ e, const int* __restrict__ sorted,
    const int* __restrict__ off, float* __restrict__ msgs, int N)
{
    int node = blockIdx.x * 4 + (threadIdx.x >> 6);
    int lane = threadIdx.x & 63;
    if (node >= N) return;
    int beg = off[node], end = off[node + 1];
    float ax = 0.f, ay = 0.f;
    for (int base = beg; base < end; base += 64) {
        int eid_l = (base + lane < end) ? sorted[base + lane] : 0;
        int cnt = min(64, end - base);
        int i = 0;
        for (; i + 4 <= cnt; i += 4) {
            int e0 = __shfl(eid_l, i), e1 = __shfl(eid_l, i + 1);
            int e2 = __shfl(eid_l, i + 2), e3 = __shfl(eid_l, i + 3);
            float2 v0 = *reinterpret_cast<const float2*>(e + (size_t)e0 * H + lane * 2);
            float2 v1 = *reinterpret_cast<const float2*>(e + (size_t)e1 * H + lane * 2);
            float2 v2 = *reinterpret_cast<const float2*>(e + (size_t)e2 * H + lane * 2);
            float2 v3 = *reinterpret_cast<const float2*>(e + (size_t)e3 * H + lane * 2);
            ax += v0.x + v1.x + v2.x + v3.x;
            ay += v0.y + v1.y + v2.y + v3.y;
        }
        for (; i < cnt; ++i) {
            int eid = __shfl(eid_l, i);
            float2 v = *reinterpret_cast<const float2*>(e + (size_t)eid * H + lane * 2);
            ax += v.x; ay += v.y;
        }
    }
    float2 r = make_float2(ax, ay);
    *reinterpret_cast<float2*>(msgs + (size_t)node * H + lane * 2) = r;
}

// ---------------------------------------------------------------------------
// Weight prep: W[K][128] fp32  ->  Wt[128][K] bf16  (B-operand layout)
// ---------------------------------------------------------------------------
__global__ __launch_bounds__(256) void wtrans_kernel(
    const float* __restrict__ W, ushort* __restrict__ Wt, int K)
{
    int idx = blockIdx.x * 256 + threadIdx.x;
    if (idx >= K * H) return;
    int k = idx >> 7, n = idx & (H - 1);
    Wt[n * K + k] = f2bf(W[idx]);
}

// ---------------------------------------------------------------------------
// Fused MLP via MFMA (unchanged from R2).
// ---------------------------------------------------------------------------
template<int K, bool GATHER>
__global__ __launch_bounds__(256) void mlp_mfma_kernel(
    const float* __restrict__ in0,
    const float* __restrict__ in1,
    const int* __restrict__ ei,
    const ushort* __restrict__ W1t,
    const float* __restrict__ b1,
    const float* __restrict__ g1, const float* __restrict__ be1,
    const ushort* __restrict__ W2t,
    const float* __restrict__ b2,
    const float* __restrict__ res,
    float* __restrict__ out, int M)
{
    constexpr int KP = K + 8;
    __shared__ ushort in_s[64][KP];
    __shared__ ushort h_s[64][H + 8];
    __shared__ float part_s[2][64], part_q[2][64];
    __shared__ int sidx[64], eidx[64];

    const int tid = threadIdx.x;
    const int row0 = blockIdx.x * 64;

    if constexpr (GATHER) {
        if (tid < 64) {
            int row = row0 + tid;
            sidx[tid] = (row < M) ? ei[row] : 0;
            eidx[tid] = (row < M) ? ei[M + row] : 0;
        }
        __syncthreads();
    }

    constexpr int C4 = K / 4;
    for (int idx = tid; idx < 64 * C4; idx += 256) {
        int r = idx / C4, c4 = idx % C4;
        int row = row0 + r;
        float4 v = make_float4(0.f, 0.f, 0.f, 0.f);
        if (row < M) {
            if constexpr (GATHER) {
                if (c4 < H / 4)
                    v = reinterpret_cast<const float4*>(in0 + (long long)sidx[r] * H)[c4];
                else if (c4 < 2 * (H / 4))
                    v = reinterpret_cast<const float4*>(in0 + (long long)eidx[r] * H)[c4 - H / 4];
                else
                    v = reinterpret_cast<const float4*>(in1 + (long long)row * H)[c4 - 2 * (H / 4)];
            } else {
                if (c4 < H / 4)
                    v = reinterpret_cast<const float4*>(in0 + (long long)row * H)[c4];
                else
                    v = reinterpret_cast<const float4*>(in1 + (long long)row * H)[c4 - H / 4];
            }
        }
        ushort4 bv;
        bv.x = f2bf(v.x); bv.y = f2bf(v.y); bv.z = f2bf(v.z); bv.w = f2bf(v.w);
        *reinterpret_cast<ushort4*>(&in_s[r][c4 * 4]) = bv;
    }
    __syncthreads();

    const int lane = tid & 63;
    const int w    = tid >> 6;
    const int l15  = lane & 15;
    const int lg   = lane >> 4;
    const int mrow = (w & 1) * 32;
    const int ncol = (w >> 1) * 64;

    f32x4 acc[2][4];
    #pragma unroll
    for (int mt = 0; mt < 2; ++mt)
        #pragma unroll
        for (int nt = 0; nt < 4; ++nt)
            acc[mt][nt] = (f32x4){0.f, 0.f, 0.f, 0.f};

    #pragma unroll 2
    for (int ks = 0; ks < K / 32; ++ks) {
        int k0 = ks * 32 + lg * 8;
        bf16x8 a0 = *reinterpret_cast<const bf16x8*>(&in_s[mrow + l15][k0]);
        bf16x8 a1 = *reinterpret_cast<const bf16x8*>(&in_s[mrow + 16 + l15][k0]);
        #pragma unroll
        for (int nt = 0; nt < 4; ++nt) {
            bf16x8 bfr = *reinterpret_cast<const bf16x8*>(
                &W1t[(size_t)(ncol + nt * 16 + l15) * K + k0]);
            acc[0][nt] = mfma16(a0, bfr, acc[0][nt]);
            acc[1][nt] = mfma16(a1, bfr, acc[1][nt]);
        }
    }

    float b1c[4], g1c[4], be1c[4];
    #pragma unroll
    for (int nt = 0; nt < 4; ++nt) {
        int c = ncol + nt * 16 + l15;
        b1c[nt] = b1[c]; g1c[nt] = g1[c]; be1c[nt] = be1[c];
    }
    #pragma unroll
    for (int mt = 0; mt < 2; ++mt)
        #pragma unroll
        for (int nt = 0; nt < 4; ++nt)
            #pragma unroll
            for (int r = 0; r < 4; ++r)
                acc[mt][nt][r] += b1c[nt];

    #pragma unroll
    for (int mt = 0; mt < 2; ++mt) {
        #pragma unroll
        for (int r = 0; r < 4; ++r) {
            float s = acc[mt][0][r] + acc[mt][1][r] + acc[mt][2][r] + acc[mt][3][r];
            float q = acc[mt][0][r] * acc[mt][0][r] + acc[mt][1][r] * acc[mt][1][r]
                    + acc[mt][2][r] * acc[mt][2][r] + acc[mt][3][r] * acc[mt][3][r];
            #pragma unroll
            for (int m = 8; m >= 1; m >>= 1) {
                s += __shfl_xor(s, m);
                q += __shfl_xor(q, m);
            }
            if (l15 == 0) {
                int rl = mrow + mt * 16 + lg * 4 + r;
                part_s[w >> 1][rl] = s;
                part_q[w >> 1][rl] = q;
            }
        }
    }
    __syncthreads();

    #pragma unroll
    for (int mt = 0; mt < 2; ++mt) {
        #pragma unroll
        for (int r = 0; r < 4; ++r) {
            int rl = mrow + mt * 16 + lg * 4 + r;
            float s  = part_s[0][rl] + part_s[1][rl];
            float q  = part_q[0][rl] + part_q[1][rl];
            float mu = s * (1.0f / H);
            float rs = rsqrtf(q * (1.0f / H) - mu * mu + LN_EPS);
            #pragma unroll
            for (int nt = 0; nt < 4; ++nt) {
                float v = (acc[mt][nt][r] - mu) * rs * g1c[nt] + be1c[nt];
                v = v / (1.0f + __expf(-v));
                h_s[rl][ncol + nt * 16 + l15] = f2bf(v);
            }
        }
    }
    __syncthreads();

    f32x4 acc2[2][4];
    #pragma unroll
    for (int nt = 0; nt < 4; ++nt) {
        float bb = b2[ncol + nt * 16 + l15];
        #pragma unroll
        for (int mt = 0; mt < 2; ++mt)
            acc2[mt][nt] = (f32x4){bb, bb, bb, bb};
    }
    #pragma unroll
    for (int ks = 0; ks < H / 32; ++ks) {
        int k0 = ks * 32 + lg * 8;
        bf16x8 a0 = *reinterpret_cast<const bf16x8*>(&h_s[mrow + l15][k0]);
        bf16x8 a1 = *reinterpret_cast<const bf16x8*>(&h_s[mrow + 16 + l15][k0]);
        #pragma unroll
        for (int nt = 0; nt < 4; ++nt) {
            bf16x8 bfr = *reinterpret_cast<const bf16x8*>(
                &W2t[(size_t)(ncol + nt * 16 + l15) * H + k0]);
            acc2[0][nt] = mfma16(a0, bfr, acc2[0][nt]);
            acc2[1][nt] = mfma16(a1, bfr, acc2[1][nt]);
        }
    }

    #pragma unroll
    for (int mt = 0; mt < 2; ++mt) {
        #pragma unroll
        for (int r = 0; r < 4; ++r) {
            int row = row0 + mrow + mt * 16 + lg * 4 + r;
            if (row < M) {
                const float* rp = res + (size_t)row * H;
                float* op = out + (size_t)row * H;
                #pragma unroll
                for (int nt = 0; nt < 4; ++nt) {
                    int c = ncol + nt * 16 + l15;
                    op[c] = acc2[mt][nt][r] + rp[c];
                }
            }
        }
    }
}

// ---------------------------------------------------------------------------
extern "C" void kernel_launch(void* const* d_in, const int* in_sizes, int n_in,
                              void* d_out, int out_size, void* d_ws, size_t ws_size,
                              hipStream_t stream)
{
    const float* x     = (const float*)d_in[0];
    const int*   ei    = (const int*)  d_in[1];
    const float* e     = (const float*)d_in[2];
    const float* Wn1   = (const float*)d_in[3];
    const float* bn1   = (const float*)d_in[4];
    const float* gn1   = (const float*)d_in[5];
    const float* betan1= (const float*)d_in[6];
    const float* Wn2   = (const float*)d_in[7];
    const float* bn2   = (const float*)d_in[8];
    const float* We1   = (const float*)d_in[9];
    const float* be1   = (const float*)d_in[10];
    const float* ge1   = (const float*)d_in[11];
    const float* betae1= (const float*)d_in[12];
    const float* We2   = (const float*)d_in[13];
    const float* be2   = (const float*)d_in[14];

    const int N = in_sizes[0] / H;
    const int E = in_sizes[2] / H;

    float* x_out = (float*)d_out;
    float* e_out = (float*)d_out + (long long)N * H;

    // workspace layout
    char* p = (char*)d_ws;
    float*  msgs = (float*)p;            p += (size_t)N * H * sizeof(float);
    ushort* Wn1t = (ushort*)p;           p += (size_t)256 * H * sizeof(ushort);
    ushort* Wn2t = (ushort*)p;           p += (size_t)H * H * sizeof(ushort);
    ushort* We1t = (ushort*)p;           p += (size_t)384 * H * sizeof(ushort);
    ushort* We2t = (ushort*)p;           p += (size_t)H * H * sizeof(ushort);
    p = (char*)(((size_t)p + 15) & ~(size_t)15);
    int* cnt    = (int*)p;               p += (size_t)N * sizeof(int);
    int* off    = (int*)p;               p += ((size_t)N + 1) * sizeof(int);
    int* cursor = (int*)p;               p += (size_t)N * sizeof(int);
    int* sorted = (int*)p;               p += (size_t)E * sizeof(int);

    // weights -> bf16 transposed
    wtrans_kernel<<<(256 * H + 255) / 256, 256, 0, stream>>>(Wn1, Wn1t, 256);
    wtrans_kernel<<<(H * H + 255) / 256, 256, 0, stream>>>(Wn2, Wn2t, H);
    wtrans_kernel<<<(384 * H + 255) / 256, 256, 0, stream>>>(We1, We1t, 384);
    wtrans_kernel<<<(H * H + 255) / 256, 256, 0, stream>>>(We2, We2t, H);

    // counting sort by destination
    hipMemsetAsync(cnt, 0, (size_t)N * sizeof(int), stream);
    hist_kernel<<<(E + 255) / 256, 256, 0, stream>>>(ei, cnt, E);
    scan_kernel<<<1, 1024, 0, stream>>>(cnt, off, N);
    hipMemcpyAsync(cursor, off, (size_t)N * sizeof(int),
                   hipMemcpyDeviceToDevice, stream);
    reorder_kernel<<<(E + 255) / 256, 256, 0, stream>>>(ei, cursor, sorted, E);

    // gather segment-sum: one wave per node
    segsum_kernel<<<(N + 3) / 4, 256, 0, stream>>>(e, sorted, off, msgs, N);

    {
        int blocks = (N + 63) / 64;
        mlp_mfma_kernel<256, false><<<blocks, 256, 0, stream>>>(
            x, msgs, nullptr, Wn1t, bn1, gn1, betan1, Wn2t, bn2, x, x_out, N);
    }
    {
        int blocks = (E + 63) / 64;
        mlp_mfma_kernel<384, true><<<blocks, 256, 0, stream>>>(
            x_out, e, ei, We1t, be1, ge1, betae1, We2t, be2, e, e_out, E);
    }
}

// Round 4
// 938.794 us; speedup vs baseline: 4.3222x; 1.4399x over previous
//
#include <hip/hip_runtime.h>

#define H 128
#define LN_EPS 1e-5f

typedef __attribute__((ext_vector_type(8))) short bf16x8;
typedef __attribute__((ext_vector_type(4))) float f32x4;

__device__ __forceinline__ ushort f2bf(float f) {
    unsigned u = __builtin_bit_cast(unsigned, f);
    u += 0x7fffu + ((u >> 16) & 1u);          // RNE
    return (ushort)(u >> 16);
}

// pack 8 fp32 -> bf16x8 via v_cvt_pk_bf16_f32 (RNE), 4 instrs
__device__ __forceinline__ bf16x8 cvt8(float4 lo, float4 hi) {
    union { bf16x8 v; unsigned u[4]; } r;
    asm("v_cvt_pk_bf16_f32 %0, %1, %2" : "=v"(r.u[0]) : "v"(lo.x), "v"(lo.y));
    asm("v_cvt_pk_bf16_f32 %0, %1, %2" : "=v"(r.u[1]) : "v"(lo.z), "v"(lo.w));
    asm("v_cvt_pk_bf16_f32 %0, %1, %2" : "=v"(r.u[2]) : "v"(hi.x), "v"(hi.y));
    asm("v_cvt_pk_bf16_f32 %0, %1, %2" : "=v"(r.u[3]) : "v"(hi.z), "v"(hi.w));
    return r.v;
}

__device__ __forceinline__ f32x4 mfma16(bf16x8 a, bf16x8 b, f32x4 c) {
    return __builtin_amdgcn_mfma_f32_16x16x32_bf16(a, b, c, 0, 0, 0);
}

// ---------------------------------------------------------------------------
// counting-sort by destination, then gather-sum (replaces atomic scatter)
// ---------------------------------------------------------------------------
__global__ __launch_bounds__(256) void hist_kernel(
    const int* __restrict__ ei, int* __restrict__ cnt, int E)
{
    int i = blockIdx.x * 256 + threadIdx.x;
    if (i < E) atomicAdd(&cnt[ei[E + i]], 1);
}

__global__ __launch_bounds__(1024) void scan_kernel(
    const int* __restrict__ cnt, int* __restrict__ off, int N)
{
    __shared__ int s[1024];
    const int t = threadIdx.x;
    const int chunk = (N + 1023) / 1024;
    const int lo = t * chunk, hi = min(lo + chunk, N);
    int sum = 0;
    for (int i = lo; i < hi; ++i) sum += cnt[i];
    s[t] = sum;
    __syncthreads();
    for (int d = 1; d < 1024; d <<= 1) {
        int v = (t >= d) ? s[t - d] : 0;
        __syncthreads();
        s[t] += v;
        __syncthreads();
    }
    int running = s[t] - sum;
    for (int i = lo; i < hi; ++i) {
        off[i] = running;
        running += cnt[i];
    }
    if (t == 1023) off[N] = running;
}

__global__ __launch_bounds__(256) void reorder_kernel(
    const int* __restrict__ ei, int* __restrict__ cursor,
    int* __restrict__ sorted, int E)
{
    int i = blockIdx.x * 256 + threadIdx.x;
    if (i < E) {
        int pos = atomicAdd(&cursor[ei[E + i]], 1);
        sorted[pos] = i;
    }
}

__global__ __launch_bounds__(256) void segsum_kernel(
    const float* __restrict__ e, const int* __restrict__ sorted,
    const int* __restrict__ off, float* __restrict__ msgs, int N)
{
    int node = blockIdx.x * 4 + (threadIdx.x >> 6);
    int lane = threadIdx.x & 63;
    if (node >= N) return;
    int beg = off[node], end = off[node + 1];
    float ax = 0.f, ay = 0.f;
    for (int base = beg; base < end; base += 64) {
        int eid_l = (base + lane < end) ? sorted[base + lane] : 0;
        int cnt = min(64, end - base);
        int i = 0;
        for (; i + 4 <= cnt; i += 4) {
            int e0 = __shfl(eid_l, i), e1 = __shfl(eid_l, i + 1);
            int e2 = __shfl(eid_l, i + 2), e3 = __shfl(eid_l, i + 3);
            float2 v0 = *reinterpret_cast<const float2*>(e + (size_t)e0 * H + lane * 2);
            float2 v1 = *reinterpret_cast<const float2*>(e + (size_t)e1 * H + lane * 2);
            float2 v2 = *reinterpret_cast<const float2*>(e + (size_t)e2 * H + lane * 2);
            float2 v3 = *reinterpret_cast<const float2*>(e + (size_t)e3 * H + lane * 2);
            ax += v0.x + v1.x + v2.x + v3.x;
            ay += v0.y + v1.y + v2.y + v3.y;
        }
        for (; i < cnt; ++i) {
            int eid = __shfl(eid_l, i);
            float2 v = *reinterpret_cast<const float2*>(e + (size_t)eid * H + lane * 2);
            ax += v.x; ay += v.y;
        }
    }
    *reinterpret_cast<float2*>(msgs + (size_t)node * H + lane * 2) = make_float2(ax, ay);
}

// ---------------------------------------------------------------------------
// W[K][128] fp32 -> Wt[128][K] bf16
// ---------------------------------------------------------------------------
__global__ __launch_bounds__(256) void wtrans_kernel(
    const float* __restrict__ W, ushort* __restrict__ Wt, int K)
{
    int idx = blockIdx.x * 256 + threadIdx.x;
    if (idx >= K * H) return;
    int k = idx >> 7, n = idx & (H - 1);
    Wt[n * K + k] = f2bf(W[idx]);
}

// ---------------------------------------------------------------------------
// Node MLP: [x|msgs](256) -> L1 -> LN -> SiLU -> L2 -> +x.  64 rows/block.
// LDS: in staged bf16 [64][264]; h aliased onto same buffer [64][136].
// ---------------------------------------------------------------------------
__global__ __launch_bounds__(256, 4) void node_mlp_kernel(
    const float* __restrict__ x, const float* __restrict__ msgs,
    const ushort* __restrict__ W1t, const float* __restrict__ b1,
    const float* __restrict__ g1, const float* __restrict__ be1,
    const ushort* __restrict__ W2t, const float* __restrict__ b2,
    float* __restrict__ x_out, int N)
{
    __shared__ ushort smem[64 * 264];           // 33.8 KB; h [64][136] aliases
    __shared__ float part_s[2][64], part_q[2][64];

    const int tid = threadIdx.x;
    const int row0 = blockIdx.x * 64;

    for (int idx = tid; idx < 64 * 64; idx += 256) {
        int r = idx >> 6, c4 = idx & 63;
        int row = row0 + r;
        float4 v = make_float4(0.f, 0.f, 0.f, 0.f);
        if (row < N)
            v = (c4 < 32) ? reinterpret_cast<const float4*>(x + (size_t)row * H)[c4]
                          : reinterpret_cast<const float4*>(msgs + (size_t)row * H)[c4 - 32];
        ushort4 bv;
        bv.x = f2bf(v.x); bv.y = f2bf(v.y); bv.z = f2bf(v.z); bv.w = f2bf(v.w);
        *reinterpret_cast<ushort4*>(&smem[r * 264 + c4 * 4]) = bv;
    }
    __syncthreads();

    const int lane = tid & 63, w = tid >> 6;
    const int l15 = lane & 15, lg = lane >> 4;
    const int mrow = (w & 1) * 32, ncol = (w >> 1) * 64;

    const ushort* pi0 = smem + (size_t)(mrow + l15) * 264;
    const ushort* pi1 = smem + (size_t)(mrow + 16 + l15) * 264;
    const ushort* pw1 = W1t + (size_t)(ncol + l15) * 256;

    f32x4 acc[2][4];
    #pragma unroll
    for (int mt = 0; mt < 2; ++mt)
        #pragma unroll
        for (int nt = 0; nt < 4; ++nt)
            acc[mt][nt] = (f32x4){0.f, 0.f, 0.f, 0.f};

    #pragma unroll
    for (int ks = 0; ks < 8; ++ks) {
        int k0 = ks * 32 + lg * 8;
        bf16x8 a0 = *reinterpret_cast<const bf16x8*>(pi0 + k0);
        bf16x8 a1 = *reinterpret_cast<const bf16x8*>(pi1 + k0);
        #pragma unroll
        for (int nt = 0; nt < 4; ++nt) {
            bf16x8 bfr = *reinterpret_cast<const bf16x8*>(pw1 + (size_t)nt * 16 * 256 + k0);
            acc[0][nt] = mfma16(a0, bfr, acc[0][nt]);
            acc[1][nt] = mfma16(a1, bfr, acc[1][nt]);
        }
    }

    float b1c[4], g1c[4], be1c[4];
    #pragma unroll
    for (int nt = 0; nt < 4; ++nt) {
        int c = ncol + nt * 16 + l15;
        b1c[nt] = b1[c]; g1c[nt] = g1[c]; be1c[nt] = be1[c];
    }
    #pragma unroll
    for (int mt = 0; mt < 2; ++mt)
        #pragma unroll
        for (int nt = 0; nt < 4; ++nt)
            #pragma unroll
            for (int r = 0; r < 4; ++r)
                acc[mt][nt][r] += b1c[nt];

    #pragma unroll
    for (int mt = 0; mt < 2; ++mt) {
        #pragma unroll
        for (int r = 0; r < 4; ++r) {
            float s = acc[mt][0][r] + acc[mt][1][r] + acc[mt][2][r] + acc[mt][3][r];
            float q = acc[mt][0][r] * acc[mt][0][r] + acc[mt][1][r] * acc[mt][1][r]
                    + acc[mt][2][r] * acc[mt][2][r] + acc[mt][3][r] * acc[mt][3][r];
            #pragma unroll
            for (int m = 8; m >= 1; m >>= 1) {
                s += __shfl_xor(s, m);
                q += __shfl_xor(q, m);
            }
            if (l15 == 0) {
                int rl = mrow + mt * 16 + lg * 4 + r;
                part_s[w >> 1][rl] = s;
                part_q[w >> 1][rl] = q;
            }
        }
    }
    __syncthreads();   // all waves done with matmul1 -> smem reusable for h

    #pragma unroll
    for (int mt = 0; mt < 2; ++mt) {
        #pragma unroll
        for (int r = 0; r < 4; ++r) {
            int rl = mrow + mt * 16 + lg * 4 + r;
            float s  = part_s[0][rl] + part_s[1][rl];
            float q  = part_q[0][rl] + part_q[1][rl];
            float mu = s * (1.0f / H);
            float rs = rsqrtf(q * (1.0f / H) - mu * mu + LN_EPS);
            #pragma unroll
            for (int nt = 0; nt < 4; ++nt) {
                float v = (acc[mt][nt][r] - mu) * rs * g1c[nt] + be1c[nt];
                v = v / (1.0f + __expf(-v));
                smem[rl * 136 + ncol + nt * 16 + l15] = f2bf(v);
            }
        }
    }
    __syncthreads();

    const ushort* ph0 = smem + (size_t)(mrow + l15) * 136;
    const ushort* ph1 = smem + (size_t)(mrow + 16 + l15) * 136;
    const ushort* pw2 = W2t + (size_t)(ncol + l15) * 128;

    f32x4 acc2[2][4];
    #pragma unroll
    for (int nt = 0; nt < 4; ++nt) {
        float bb = b2[ncol + nt * 16 + l15];
        #pragma unroll
        for (int mt = 0; mt < 2; ++mt)
            acc2[mt][nt] = (f32x4){bb, bb, bb, bb};
    }
    #pragma unroll
    for (int ks = 0; ks < 4; ++ks) {
        int k0 = ks * 32 + lg * 8;
        bf16x8 a0 = *reinterpret_cast<const bf16x8*>(ph0 + k0);
        bf16x8 a1 = *reinterpret_cast<const bf16x8*>(ph1 + k0);
        #pragma unroll
        for (int nt = 0; nt < 4; ++nt) {
            bf16x8 bfr = *reinterpret_cast<const bf16x8*>(pw2 + (size_t)nt * 16 * 128 + k0);
            acc2[0][nt] = mfma16(a0, bfr, acc2[0][nt]);
            acc2[1][nt] = mfma16(a1, bfr, acc2[1][nt]);
        }
    }

    #pragma unroll
    for (int mt = 0; mt < 2; ++mt) {
        #pragma unroll
        for (int r = 0; r < 4; ++r) {
            int row = row0 + mrow + mt * 16 + lg * 4 + r;
            if (row < N) {
                const float* rp = x + (size_t)row * H;
                float* op = x_out + (size_t)row * H;
                #pragma unroll
                for (int nt = 0; nt < 4; ++nt) {
                    int c = ncol + nt * 16 + l15;
                    op[c] = acc2[mt][nt][r] + rp[c];
                }
            }
        }
    }
}

// ---------------------------------------------------------------------------
// Edge MLP: [x_out[s]|x_out[d]|e](384) -> L1 -> LN -> SiLU -> L2 -> +e.
// x_out parts: per-lane gather from global fp32 (L2/L3-resident) + cvt_pk.
// e part: staged bf16 in LDS (coalesced), buffer aliased with h after matmul1.
// ---------------------------------------------------------------------------
__global__ __launch_bounds__(256, 4) void edge_mlp_kernel(
    const float* __restrict__ x_out, const float* __restrict__ e,
    const int* __restrict__ ei,
    const ushort* __restrict__ W1t, const float* __restrict__ b1,
    const float* __restrict__ g1, const float* __restrict__ be1,
    const ushort* __restrict__ W2t, const float* __restrict__ b2,
    float* __restrict__ e_out, int E)
{
    __shared__ ushort smem[64 * 136];           // e-part (phase1) / h (phase2)
    __shared__ float part_s[2][64], part_q[2][64];
    __shared__ int sidx[64], eidx[64];

    const int tid = threadIdx.x;
    const int row0 = blockIdx.x * 64;

    if (tid < 64) {
        int row = row0 + tid;
        sidx[tid] = (row < E) ? ei[row] : 0;
        eidx[tid] = (row < E) ? ei[E + row] : 0;
    }

    // stage e rows -> bf16 LDS (64 rows x 128 cols)
    for (int idx = tid; idx < 64 * 32; idx += 256) {
        int r = idx >> 5, c4 = idx & 31;
        int row = row0 + r;
        float4 v = make_float4(0.f, 0.f, 0.f, 0.f);
        if (row < E)
            v = reinterpret_cast<const float4*>(e + (size_t)row * H)[c4];
        ushort4 bv;
        bv.x = f2bf(v.x); bv.y = f2bf(v.y); bv.z = f2bf(v.z); bv.w = f2bf(v.w);
        *reinterpret_cast<ushort4*>(&smem[r * 136 + c4 * 4]) = bv;
    }
    __syncthreads();

    const int lane = tid & 63, w = tid >> 6;
    const int l15 = lane & 15, lg = lane >> 4;
    const int mrow = (w & 1) * 32, ncol = (w >> 1) * 64;
    const int rA0 = mrow + l15, rA1 = mrow + 16 + l15;

    const float* pxs0 = x_out + (size_t)sidx[rA0] * H;
    const float* pxs1 = x_out + (size_t)sidx[rA1] * H;
    const float* pxd0 = x_out + (size_t)eidx[rA0] * H;
    const float* pxd1 = x_out + (size_t)eidx[rA1] * H;
    const ushort* pe0 = smem + (size_t)rA0 * 136;
    const ushort* pe1 = smem + (size_t)rA1 * 136;
    const ushort* pw1 = W1t + (size_t)(ncol + l15) * 384;

    f32x4 acc[2][4];
    #pragma unroll
    for (int mt = 0; mt < 2; ++mt)
        #pragma unroll
        for (int nt = 0; nt < 4; ++nt)
            acc[mt][nt] = (f32x4){0.f, 0.f, 0.f, 0.f};

    #pragma unroll
    for (int ks = 0; ks < 12; ++ks) {
        int k0 = ks * 32 + lg * 8;
        bf16x8 a0, a1;
        if (ks < 4) {
            a0 = cvt8(*reinterpret_cast<const float4*>(pxs0 + k0),
                      *reinterpret_cast<const float4*>(pxs0 + k0 + 4));
            a1 = cvt8(*reinterpret_cast<const float4*>(pxs1 + k0),
                      *reinterpret_cast<const float4*>(pxs1 + k0 + 4));
        } else if (ks < 8) {
            a0 = cvt8(*reinterpret_cast<const float4*>(pxd0 + k0 - 128),
                      *reinterpret_cast<const float4*>(pxd0 + k0 - 124));
            a1 = cvt8(*reinterpret_cast<const float4*>(pxd1 + k0 - 128),
                      *reinterpret_cast<const float4*>(pxd1 + k0 - 124));
        } else {
            a0 = *reinterpret_cast<const bf16x8*>(pe0 + (k0 - 256));
            a1 = *reinterpret_cast<const bf16x8*>(pe1 + (k0 - 256));
        }
        #pragma unroll
        for (int nt = 0; nt < 4; ++nt) {
            bf16x8 bfr = *reinterpret_cast<const bf16x8*>(pw1 + (size_t)nt * 16 * 384 + k0);
            acc[0][nt] = mfma16(a0, bfr, acc[0][nt]);
            acc[1][nt] = mfma16(a1, bfr, acc[1][nt]);
        }
    }

    float b1c[4], g1c[4], be1c[4];
    #pragma unroll
    for (int nt = 0; nt < 4; ++nt) {
        int c = ncol + nt * 16 + l15;
        b1c[nt] = b1[c]; g1c[nt] = g1[c]; be1c[nt] = be1[c];
    }
    #pragma unroll
    for (int mt = 0; mt < 2; ++mt)
        #pragma unroll
        for (int nt = 0; nt < 4; ++nt)
            #pragma unroll
            for (int r = 0; r < 4; ++r)
                acc[mt][nt][r] += b1c[nt];

    #pragma unroll
    for (int mt = 0; mt < 2; ++mt) {
        #pragma unroll
        for (int r = 0; r < 4; ++r) {
            float s = acc[mt][0][r] + acc[mt][1][r] + acc[mt][2][r] + acc[mt][3][r];
            float q = acc[mt][0][r] * acc[mt][0][r] + acc[mt][1][r] * acc[mt][1][r]
                    + acc[mt][2][r] * acc[mt][2][r] + acc[mt][3][r] * acc[mt][3][r];
            #pragma unroll
            for (int m = 8; m >= 1; m >>= 1) {
                s += __shfl_xor(s, m);
                q += __shfl_xor(q, m);
            }
            if (l15 == 0) {
                int rl = mrow + mt * 16 + lg * 4 + r;
                part_s[w >> 1][rl] = s;
                part_q[w >> 1][rl] = q;
            }
        }
    }
    __syncthreads();   // all waves past matmul1 -> smem (e) reusable for h

    #pragma unroll
    for (int mt = 0; mt < 2; ++mt) {
        #pragma unroll
        for (int r = 0; r < 4; ++r) {
            int rl = mrow + mt * 16 + lg * 4 + r;
            float s  = part_s[0][rl] + part_s[1][rl];
            float q  = part_q[0][rl] + part_q[1][rl];
            float mu = s * (1.0f / H);
            float rs = rsqrtf(q * (1.0f / H) - mu * mu + LN_EPS);
            #pragma unroll
            for (int nt = 0; nt < 4; ++nt) {
                float v = (acc[mt][nt][r] - mu) * rs * g1c[nt] + be1c[nt];
                v = v / (1.0f + __expf(-v));
                smem[rl * 136 + ncol + nt * 16 + l15] = f2bf(v);
            }
        }
    }
    __syncthreads();

    const ushort* ph0 = smem + (size_t)rA0 * 136;
    const ushort* ph1 = smem + (size_t)rA1 * 136;
    const ushort* pw2 = W2t + (size_t)(ncol + l15) * 128;

    f32x4 acc2[2][4];
    #pragma unroll
    for (int nt = 0; nt < 4; ++nt) {
        float bb = b2[ncol + nt * 16 + l15];
        #pragma unroll
        for (int mt = 0; mt < 2; ++mt)
            acc2[mt][nt] = (f32x4){bb, bb, bb, bb};
    }
    #pragma unroll
    for (int ks = 0; ks < 4; ++ks) {
        int k0 = ks * 32 + lg * 8;
        bf16x8 a0 = *reinterpret_cast<const bf16x8*>(ph0 + k0);
        bf16x8 a1 = *reinterpret_cast<const bf16x8*>(ph1 + k0);
        #pragma unroll
        for (int nt = 0; nt < 4; ++nt) {
            bf16x8 bfr = *reinterpret_cast<const bf16x8*>(pw2 + (size_t)nt * 16 * 128 + k0);
            acc2[0][nt] = mfma16(a0, bfr, acc2[0][nt]);
            acc2[1][nt] = mfma16(a1, bfr, acc2[1][nt]);
        }
    }

    #pragma unroll
    for (int mt = 0; mt < 2; ++mt) {
        #pragma unroll
        for (int r = 0; r < 4; ++r) {
            int row = row0 + mrow + mt * 16 + lg * 4 + r;
            if (row < E) {
                const float* rp = e + (size_t)row * H;
                float* op = e_out + (size_t)row * H;
                #pragma unroll
                for (int nt = 0; nt < 4; ++nt) {
                    int c = ncol + nt * 16 + l15;
                    op[c] = acc2[mt][nt][r] + rp[c];
                }
            }
        }
    }
}

// ---------------------------------------------------------------------------
extern "C" void kernel_launch(void* const* d_in, const int* in_sizes, int n_in,
                              void* d_out, int out_size, void* d_ws, size_t ws_size,
                              hipStream_t stream)
{
    const float* x     = (const float*)d_in[0];
    const int*   ei    = (const int*)  d_in[1];
    const float* e     = (const float*)d_in[2];
    const float* Wn1   = (const float*)d_in[3];
    const float* bn1   = (const float*)d_in[4];
    const float* gn1   = (const float*)d_in[5];
    const float* betan1= (const float*)d_in[6];
    const float* Wn2   = (const float*)d_in[7];
    const float* bn2   = (const float*)d_in[8];
    const float* We1   = (const float*)d_in[9];
    const float* be1   = (const float*)d_in[10];
    const float* ge1   = (const float*)d_in[11];
    const float* betae1= (const float*)d_in[12];
    const float* We2   = (const float*)d_in[13];
    const float* be2   = (const float*)d_in[14];

    const int N = in_sizes[0] / H;
    const int E = in_sizes[2] / H;

    float* x_out = (float*)d_out;
    float* e_out = (float*)d_out + (long long)N * H;

    char* p = (char*)d_ws;
    float*  msgs = (float*)p;            p += (size_t)N * H * sizeof(float);
    ushort* Wn1t = (ushort*)p;           p += (size_t)256 * H * sizeof(ushort);
    ushort* Wn2t = (ushort*)p;           p += (size_t)H * H * sizeof(ushort);
    ushort* We1t = (ushort*)p;           p += (size_t)384 * H * sizeof(ushort);
    ushort* We2t = (ushort*)p;           p += (size_t)H * H * sizeof(ushort);
    p = (char*)(((size_t)p + 15) & ~(size_t)15);
    int* cnt    = (int*)p;               p += (size_t)N * sizeof(int);
    int* off    = (int*)p;               p += ((size_t)N + 1) * sizeof(int);
    int* cursor = (int*)p;               p += (size_t)N * sizeof(int);
    int* sorted = (int*)p;               p += (size_t)E * sizeof(int);

    wtrans_kernel<<<(256 * H + 255) / 256, 256, 0, stream>>>(Wn1, Wn1t, 256);
    wtrans_kernel<<<(H * H + 255) / 256, 256, 0, stream>>>(Wn2, Wn2t, H);
    wtrans_kernel<<<(384 * H + 255) / 256, 256, 0, stream>>>(We1, We1t, 384);
    wtrans_kernel<<<(H * H + 255) / 256, 256, 0, stream>>>(We2, We2t, H);

    hipMemsetAsync(cnt, 0, (size_t)N * sizeof(int), stream);
    hist_kernel<<<(E + 255) / 256, 256, 0, stream>>>(ei, cnt, E);
    scan_kernel<<<1, 1024, 0, stream>>>(cnt, off, N);
    hipMemcpyAsync(cursor, off, (size_t)N * sizeof(int),
                   hipMemcpyDeviceToDevice, stream);
    reorder_kernel<<<(E + 255) / 256, 256, 0, stream>>>(ei, cursor, sorted, E);
    segsum_kernel<<<(N + 3) / 4, 256, 0, stream>>>(e, sorted, off, msgs, N);

    {
        int blocks = (N + 63) / 64;
        node_mlp_kernel<<<blocks, 256, 0, stream>>>(
            x, msgs, Wn1t, bn1, gn1, betan1, Wn2t, bn2, x_out, N);
    }
    {
        int blocks = (E + 63) / 64;
        edge_mlp_kernel<<<blocks, 256, 0, stream>>>(
            x_out, e, ei, We1t, be1, ge1, betae1, We2t, be2, e_out, E);
    }
}

// Round 5
// 864.803 us; speedup vs baseline: 4.6920x; 1.0856x over previous
//
#include <hip/hip_runtime.h>

#define H 128
#define LN_EPS 1e-5f

typedef __attribute__((ext_vector_type(8))) short bf16x8;
typedef __attribute__((ext_vector_type(4))) float f32x4;

__device__ __forceinline__ ushort f2bf(float f) {
    unsigned u = __builtin_bit_cast(unsigned, f);
    u += 0x7fffu + ((u >> 16) & 1u);          // RNE
    return (ushort)(u >> 16);
}

__device__ __forceinline__ f32x4 mfma16(bf16x8 a, bf16x8 b, f32x4 c) {
    return __builtin_amdgcn_mfma_f32_16x16x32_bf16(a, b, c, 0, 0, 0);
}

// ---------------------------------------------------------------------------
// counting-sort by destination, then gather-sum (replaces atomic scatter)
// ---------------------------------------------------------------------------
__global__ __launch_bounds__(256) void hist_kernel(
    const int* __restrict__ ei, int* __restrict__ cnt, int E)
{
    int i = blockIdx.x * 256 + threadIdx.x;
    if (i < E) atomicAdd(&cnt[ei[E + i]], 1);
}

__global__ __launch_bounds__(1024) void scan_kernel(
    const int* __restrict__ cnt, int* __restrict__ off, int N)
{
    __shared__ int s[1024];
    const int t = threadIdx.x;
    const int chunk = (N + 1023) / 1024;
    const int lo = t * chunk, hi = min(lo + chunk, N);
    int sum = 0;
    for (int i = lo; i < hi; ++i) sum += cnt[i];
    s[t] = sum;
    __syncthreads();
    for (int d = 1; d < 1024; d <<= 1) {
        int v = (t >= d) ? s[t - d] : 0;
        __syncthreads();
        s[t] += v;
        __syncthreads();
    }
    int running = s[t] - sum;
    for (int i = lo; i < hi; ++i) {
        off[i] = running;
        running += cnt[i];
    }
    if (t == 1023) off[N] = running;
}

__global__ __launch_bounds__(256) void reorder_kernel(
    const int* __restrict__ ei, int* __restrict__ cursor,
    int* __restrict__ sorted, int E)
{
    int i = blockIdx.x * 256 + threadIdx.x;
    if (i < E) {
        int pos = atomicAdd(&cursor[ei[E + i]], 1);
        sorted[pos] = i;
    }
}

__global__ __launch_bounds__(256) void segsum_kernel(
    const float* __restrict__ e, const int* __restrict__ sorted,
    const int* __restrict__ off, float* __restrict__ msgs, int N)
{
    int node = blockIdx.x * 4 + (threadIdx.x >> 6);
    int lane = threadIdx.x & 63;
    if (node >= N) return;
    int beg = off[node], end = off[node + 1];
    float ax = 0.f, ay = 0.f;
    for (int base = beg; base < end; base += 64) {
        int eid_l = (base + lane < end) ? sorted[base + lane] : 0;
        int cnt = min(64, end - base);
        int i = 0;
        for (; i + 4 <= cnt; i += 4) {
            int e0 = __shfl(eid_l, i), e1 = __shfl(eid_l, i + 1);
            int e2 = __shfl(eid_l, i + 2), e3 = __shfl(eid_l, i + 3);
            float2 v0 = *reinterpret_cast<const float2*>(e + (size_t)e0 * H + lane * 2);
            float2 v1 = *reinterpret_cast<const float2*>(e + (size_t)e1 * H + lane * 2);
            float2 v2 = *reinterpret_cast<const float2*>(e + (size_t)e2 * H + lane * 2);
            float2 v3 = *reinterpret_cast<const float2*>(e + (size_t)e3 * H + lane * 2);
            ax += v0.x + v1.x + v2.x + v3.x;
            ay += v0.y + v1.y + v2.y + v3.y;
        }
        for (; i < cnt; ++i) {
            int eid = __shfl(eid_l, i);
            float2 v = *reinterpret_cast<const float2*>(e + (size_t)eid * H + lane * 2);
            ax += v.x; ay += v.y;
        }
    }
    *reinterpret_cast<float2*>(msgs + (size_t)node * H + lane * 2) = make_float2(ax, ay);
}

// ---------------------------------------------------------------------------
// W[K][128] fp32 -> Wt[128][K] bf16
// ---------------------------------------------------------------------------
__global__ __launch_bounds__(256) void wtrans_kernel(
    const float* __restrict__ W, ushort* __restrict__ Wt, int K)
{
    int idx = blockIdx.x * 256 + threadIdx.x;
    if (idx >= K * H) return;
    int k = idx >> 7, n = idx & (H - 1);
    Wt[n * K + k] = f2bf(W[idx]);
}

// ---------------------------------------------------------------------------
// Node MLP: [x|msgs](256) -> L1 -> LN -> SiLU -> L2 -> +x.
// Also emits xbf = bf16(x_out) for the edge kernel's gathers.
// ---------------------------------------------------------------------------
__global__ __launch_bounds__(256, 4) void node_mlp_kernel(
    const float* __restrict__ x, const float* __restrict__ msgs,
    const ushort* __restrict__ W1t, const float* __restrict__ b1,
    const float* __restrict__ g1, const float* __restrict__ be1,
    const ushort* __restrict__ W2t, const float* __restrict__ b2,
    float* __restrict__ x_out, ushort* __restrict__ xbf, int N)
{
    __shared__ ushort smem[64 * 264];           // in staged; h [64][136] aliases
    __shared__ float part_s[2][64], part_q[2][64];

    const int tid = threadIdx.x;
    const int row0 = blockIdx.x * 64;

    for (int idx = tid; idx < 64 * 64; idx += 256) {
        int r = idx >> 6, c4 = idx & 63;
        int row = row0 + r;
        float4 v = make_float4(0.f, 0.f, 0.f, 0.f);
        if (row < N)
            v = (c4 < 32) ? reinterpret_cast<const float4*>(x + (size_t)row * H)[c4]
                          : reinterpret_cast<const float4*>(msgs + (size_t)row * H)[c4 - 32];
        ushort4 bv;
        bv.x = f2bf(v.x); bv.y = f2bf(v.y); bv.z = f2bf(v.z); bv.w = f2bf(v.w);
        *reinterpret_cast<ushort4*>(&smem[r * 264 + c4 * 4]) = bv;
    }
    __syncthreads();

    const int lane = tid & 63, w = tid >> 6;
    const int l15 = lane & 15, lg = lane >> 4;
    const int mrow = (w & 1) * 32, ncol = (w >> 1) * 64;

    const ushort* pi0 = smem + (size_t)(mrow + l15) * 264;
    const ushort* pi1 = smem + (size_t)(mrow + 16 + l15) * 264;
    const ushort* pw1 = W1t + (size_t)(ncol + l15) * 256;

    f32x4 acc[2][4];
    #pragma unroll
    for (int mt = 0; mt < 2; ++mt)
        #pragma unroll
        for (int nt = 0; nt < 4; ++nt)
            acc[mt][nt] = (f32x4){0.f, 0.f, 0.f, 0.f};

    #pragma unroll
    for (int ks = 0; ks < 8; ++ks) {
        int k0 = ks * 32 + lg * 8;
        bf16x8 a0 = *reinterpret_cast<const bf16x8*>(pi0 + k0);
        bf16x8 a1 = *reinterpret_cast<const bf16x8*>(pi1 + k0);
        #pragma unroll
        for (int nt = 0; nt < 4; ++nt) {
            bf16x8 bfr = *reinterpret_cast<const bf16x8*>(pw1 + (size_t)nt * 16 * 256 + k0);
            acc[0][nt] = mfma16(a0, bfr, acc[0][nt]);
            acc[1][nt] = mfma16(a1, bfr, acc[1][nt]);
        }
    }

    float b1c[4], g1c[4], be1c[4];
    #pragma unroll
    for (int nt = 0; nt < 4; ++nt) {
        int c = ncol + nt * 16 + l15;
        b1c[nt] = b1[c]; g1c[nt] = g1[c]; be1c[nt] = be1[c];
    }
    #pragma unroll
    for (int mt = 0; mt < 2; ++mt)
        #pragma unroll
        for (int nt = 0; nt < 4; ++nt)
            #pragma unroll
            for (int r = 0; r < 4; ++r)
                acc[mt][nt][r] += b1c[nt];

    #pragma unroll
    for (int mt = 0; mt < 2; ++mt) {
        #pragma unroll
        for (int r = 0; r < 4; ++r) {
            float s = acc[mt][0][r] + acc[mt][1][r] + acc[mt][2][r] + acc[mt][3][r];
            float q = acc[mt][0][r] * acc[mt][0][r] + acc[mt][1][r] * acc[mt][1][r]
                    + acc[mt][2][r] * acc[mt][2][r] + acc[mt][3][r] * acc[mt][3][r];
            #pragma unroll
            for (int m = 8; m >= 1; m >>= 1) {
                s += __shfl_xor(s, m);
                q += __shfl_xor(q, m);
            }
            if (l15 == 0) {
                int rl = mrow + mt * 16 + lg * 4 + r;
                part_s[w >> 1][rl] = s;
                part_q[w >> 1][rl] = q;
            }
        }
    }
    __syncthreads();

    #pragma unroll
    for (int mt = 0; mt < 2; ++mt) {
        #pragma unroll
        for (int r = 0; r < 4; ++r) {
            int rl = mrow + mt * 16 + lg * 4 + r;
            float s  = part_s[0][rl] + part_s[1][rl];
            float q  = part_q[0][rl] + part_q[1][rl];
            float mu = s * (1.0f / H);
            float rs = rsqrtf(q * (1.0f / H) - mu * mu + LN_EPS);
            #pragma unroll
            for (int nt = 0; nt < 4; ++nt) {
                float v = (acc[mt][nt][r] - mu) * rs * g1c[nt] + be1c[nt];
                v = v / (1.0f + __expf(-v));
                smem[rl * 136 + ncol + nt * 16 + l15] = f2bf(v);
            }
        }
    }
    __syncthreads();

    const ushort* ph0 = smem + (size_t)(mrow + l15) * 136;
    const ushort* ph1 = smem + (size_t)(mrow + 16 + l15) * 136;
    const ushort* pw2 = W2t + (size_t)(ncol + l15) * 128;

    f32x4 acc2[2][4];
    #pragma unroll
    for (int nt = 0; nt < 4; ++nt) {
        float bb = b2[ncol + nt * 16 + l15];
        #pragma unroll
        for (int mt = 0; mt < 2; ++mt)
            acc2[mt][nt] = (f32x4){bb, bb, bb, bb};
    }
    #pragma unroll
    for (int ks = 0; ks < 4; ++ks) {
        int k0 = ks * 32 + lg * 8;
        bf16x8 a0 = *reinterpret_cast<const bf16x8*>(ph0 + k0);
        bf16x8 a1 = *reinterpret_cast<const bf16x8*>(ph1 + k0);
        #pragma unroll
        for (int nt = 0; nt < 4; ++nt) {
            bf16x8 bfr = *reinterpret_cast<const bf16x8*>(pw2 + (size_t)nt * 16 * 128 + k0);
            acc2[0][nt] = mfma16(a0, bfr, acc2[0][nt]);
            acc2[1][nt] = mfma16(a1, bfr, acc2[1][nt]);
        }
    }

    #pragma unroll
    for (int mt = 0; mt < 2; ++mt) {
        #pragma unroll
        for (int r = 0; r < 4; ++r) {
            int row = row0 + mrow + mt * 16 + lg * 4 + r;
            if (row < N) {
                const float* rp = x + (size_t)row * H;
                float* op = x_out + (size_t)row * H;
                ushort* bp = xbf + (size_t)row * H;
                #pragma unroll
                for (int nt = 0; nt < 4; ++nt) {
                    int c = ncol + nt * 16 + l15;
                    float o = acc2[mt][nt][r] + rp[c];
                    op[c] = o;
                    bp[c] = f2bf(o);
                }
            }
        }
    }
}

// ---------------------------------------------------------------------------
// Edge MLP: [xbf[s]|xbf[d]|e](384) -> L1 -> LN -> SiLU -> L2 -> +e.
// x gathers: bf16, ALL 16 chunks/lane register-prefetched in one burst.
// e: staged bf16 LDS; buffer aliased with h after matmul1.
// ---------------------------------------------------------------------------
__global__ __launch_bounds__(256, 4) void edge_mlp_kernel(
    const ushort* __restrict__ xbf, const float* __restrict__ e,
    const int* __restrict__ ei,
    const ushort* __restrict__ W1t, const float* __restrict__ b1,
    const float* __restrict__ g1, const float* __restrict__ be1,
    const ushort* __restrict__ W2t, const float* __restrict__ b2,
    float* __restrict__ e_out, int E)
{
    __shared__ ushort smem[64 * 136];           // e-part (phase1) / h (phase2)
    __shared__ float part_s[2][64], part_q[2][64];
    __shared__ int sidx[64], eidx[64];

    const int tid = threadIdx.x;
    const int row0 = blockIdx.x * 64;

    if (tid < 64) {
        int row = row0 + tid;
        sidx[tid] = (row < E) ? ei[row] : 0;
        eidx[tid] = (row < E) ? ei[E + row] : 0;
    }

    // stage e rows -> bf16 LDS (64 rows x 128 cols)
    for (int idx = tid; idx < 64 * 32; idx += 256) {
        int r = idx >> 5, c4 = idx & 31;
        int row = row0 + r;
        float4 v = make_float4(0.f, 0.f, 0.f, 0.f);
        if (row < E)
            v = reinterpret_cast<const float4*>(e + (size_t)row * H)[c4];
        ushort4 bv;
        bv.x = f2bf(v.x); bv.y = f2bf(v.y); bv.z = f2bf(v.z); bv.w = f2bf(v.w);
        *reinterpret_cast<ushort4*>(&smem[r * 136 + c4 * 4]) = bv;
    }
    __syncthreads();

    const int lane = tid & 63, w = tid >> 6;
    const int l15 = lane & 15, lg = lane >> 4;
    const int mrow = (w & 1) * 32, ncol = (w >> 1) * 64;
    const int rA0 = mrow + l15, rA1 = mrow + 16 + l15;

    const ushort* ps0 = xbf + (size_t)sidx[rA0] * H + lg * 8;
    const ushort* ps1 = xbf + (size_t)sidx[rA1] * H + lg * 8;
    const ushort* pd0 = xbf + (size_t)eidx[rA0] * H + lg * 8;
    const ushort* pd1 = xbf + (size_t)eidx[rA1] * H + lg * 8;

    // ---- burst-prefetch all A-fragments for the gathered x parts ----
    bf16x8 axs0[4], axs1[4], axd0[4], axd1[4];
    #pragma unroll
    for (int k = 0; k < 4; ++k) {
        axs0[k] = *reinterpret_cast<const bf16x8*>(ps0 + k * 32);
        axs1[k] = *reinterpret_cast<const bf16x8*>(ps1 + k * 32);
        axd0[k] = *reinterpret_cast<const bf16x8*>(pd0 + k * 32);
        axd1[k] = *reinterpret_cast<const bf16x8*>(pd1 + k * 32);
    }

    const ushort* pe0 = smem + (size_t)rA0 * 136 + lg * 8;
    const ushort* pe1 = smem + (size_t)rA1 * 136 + lg * 8;
    const ushort* pw1 = W1t + (size_t)(ncol + l15) * 384 + lg * 8;

    f32x4 acc[2][4];
    #pragma unroll
    for (int mt = 0; mt < 2; ++mt)
        #pragma unroll
        for (int nt = 0; nt < 4; ++nt)
            acc[mt][nt] = (f32x4){0.f, 0.f, 0.f, 0.f};

    #pragma unroll
    for (int ks = 0; ks < 12; ++ks) {
        bf16x8 a0, a1;
        if (ks < 4)      { a0 = axs0[ks];     a1 = axs1[ks];     }
        else if (ks < 8) { a0 = axd0[ks - 4]; a1 = axd1[ks - 4]; }
        else {
            a0 = *reinterpret_cast<const bf16x8*>(pe0 + (ks - 8) * 32);
            a1 = *reinterpret_cast<const bf16x8*>(pe1 + (ks - 8) * 32);
        }
        #pragma unroll
        for (int nt = 0; nt < 4; ++nt) {
            bf16x8 bfr = *reinterpret_cast<const bf16x8*>(pw1 + (size_t)nt * 16 * 384 + ks * 32);
            acc[0][nt] = mfma16(a0, bfr, acc[0][nt]);
            acc[1][nt] = mfma16(a1, bfr, acc[1][nt]);
        }
    }

    float b1c[4], g1c[4], be1c[4];
    #pragma unroll
    for (int nt = 0; nt < 4; ++nt) {
        int c = ncol + nt * 16 + l15;
        b1c[nt] = b1[c]; g1c[nt] = g1[c]; be1c[nt] = be1[c];
    }
    #pragma unroll
    for (int mt = 0; mt < 2; ++mt)
        #pragma unroll
        for (int nt = 0; nt < 4; ++nt)
            #pragma unroll
            for (int r = 0; r < 4; ++r)
                acc[mt][nt][r] += b1c[nt];

    #pragma unroll
    for (int mt = 0; mt < 2; ++mt) {
        #pragma unroll
        for (int r = 0; r < 4; ++r) {
            float s = acc[mt][0][r] + acc[mt][1][r] + acc[mt][2][r] + acc[mt][3][r];
            float q = acc[mt][0][r] * acc[mt][0][r] + acc[mt][1][r] * acc[mt][1][r]
                    + acc[mt][2][r] * acc[mt][2][r] + acc[mt][3][r] * acc[mt][3][r];
            #pragma unroll
            for (int m = 8; m >= 1; m >>= 1) {
                s += __shfl_xor(s, m);
                q += __shfl_xor(q, m);
            }
            if (l15 == 0) {
                int rl = mrow + mt * 16 + lg * 4 + r;
                part_s[w >> 1][rl] = s;
                part_q[w >> 1][rl] = q;
            }
        }
    }
    __syncthreads();   // all waves past matmul1 -> smem (e) reusable for h

    #pragma unroll
    for (int mt = 0; mt < 2; ++mt) {
        #pragma unroll
        for (int r = 0; r < 4; ++r) {
            int rl = mrow + mt * 16 + lg * 4 + r;
            float s  = part_s[0][rl] + part_s[1][rl];
            float q  = part_q[0][rl] + part_q[1][rl];
            float mu = s * (1.0f / H);
            float rs = rsqrtf(q * (1.0f / H) - mu * mu + LN_EPS);
            #pragma unroll
            for (int nt = 0; nt < 4; ++nt) {
                float v = (acc[mt][nt][r] - mu) * rs * g1c[nt] + be1c[nt];
                v = v / (1.0f + __expf(-v));
                smem[rl * 136 + ncol + nt * 16 + l15] = f2bf(v);
            }
        }
    }
    __syncthreads();

    const ushort* ph0 = smem + (size_t)rA0 * 136;
    const ushort* ph1 = smem + (size_t)rA1 * 136;
    const ushort* pw2 = W2t + (size_t)(ncol + l15) * 128;

    f32x4 acc2[2][4];
    #pragma unroll
    for (int nt = 0; nt < 4; ++nt) {
        float bb = b2[ncol + nt * 16 + l15];
        #pragma unroll
        for (int mt = 0; mt < 2; ++mt)
            acc2[mt][nt] = (f32x4){bb, bb, bb, bb};
    }
    #pragma unroll
    for (int ks = 0; ks < 4; ++ks) {
        int k0 = ks * 32 + lg * 8;
        bf16x8 a0 = *reinterpret_cast<const bf16x8*>(ph0 + k0);
        bf16x8 a1 = *reinterpret_cast<const bf16x8*>(ph1 + k0);
        #pragma unroll
        for (int nt = 0; nt < 4; ++nt) {
            bf16x8 bfr = *reinterpret_cast<const bf16x8*>(pw2 + (size_t)nt * 16 * 128 + k0);
            acc2[0][nt] = mfma16(a0, bfr, acc2[0][nt]);
            acc2[1][nt] = mfma16(a1, bfr, acc2[1][nt]);
        }
    }

    #pragma unroll
    for (int mt = 0; mt < 2; ++mt) {
        #pragma unroll
        for (int r = 0; r < 4; ++r) {
            int row = row0 + mrow + mt * 16 + lg * 4 + r;
            if (row < E) {
                const float* rp = e + (size_t)row * H;
                float* op = e_out + (size_t)row * H;
                #pragma unroll
                for (int nt = 0; nt < 4; ++nt) {
                    int c = ncol + nt * 16 + l15;
                    op[c] = acc2[mt][nt][r] + rp[c];
                }
            }
        }
    }
}

// ---------------------------------------------------------------------------
extern "C" void kernel_launch(void* const* d_in, const int* in_sizes, int n_in,
                              void* d_out, int out_size, void* d_ws, size_t ws_size,
                              hipStream_t stream)
{
    const float* x     = (const float*)d_in[0];
    const int*   ei    = (const int*)  d_in[1];
    const float* e     = (const float*)d_in[2];
    const float* Wn1   = (const float*)d_in[3];
    const float* bn1   = (const float*)d_in[4];
    const float* gn1   = (const float*)d_in[5];
    const float* betan1= (const float*)d_in[6];
    const float* Wn2   = (const float*)d_in[7];
    const float* bn2   = (const float*)d_in[8];
    const float* We1   = (const float*)d_in[9];
    const float* be1   = (const float*)d_in[10];
    const float* ge1   = (const float*)d_in[11];
    const float* betae1= (const float*)d_in[12];
    const float* We2   = (const float*)d_in[13];
    const float* be2   = (const float*)d_in[14];

    const int N = in_sizes[0] / H;
    const int E = in_sizes[2] / H;

    float* x_out = (float*)d_out;
    float* e_out = (float*)d_out + (long long)N * H;

    char* p = (char*)d_ws;
    float*  msgs = (float*)p;            p += (size_t)N * H * sizeof(float);
    ushort* xbf  = (ushort*)p;           p += (size_t)N * H * sizeof(ushort);
    ushort* Wn1t = (ushort*)p;           p += (size_t)256 * H * sizeof(ushort);
    ushort* Wn2t = (ushort*)p;           p += (size_t)H * H * sizeof(ushort);
    ushort* We1t = (ushort*)p;           p += (size_t)384 * H * sizeof(ushort);
    ushort* We2t = (ushort*)p;           p += (size_t)H * H * sizeof(ushort);
    p = (char*)(((size_t)p + 15) & ~(size_t)15);
    int* cnt    = (int*)p;               p += (size_t)N * sizeof(int);
    int* off    = (int*)p;               p += ((size_t)N + 1) * sizeof(int);
    int* cursor = (int*)p;               p += (size_t)N * sizeof(int);
    int* sorted = (int*)p;               p += (size_t)E * sizeof(int);

    wtrans_kernel<<<(256 * H + 255) / 256, 256, 0, stream>>>(Wn1, Wn1t, 256);
    wtrans_kernel<<<(H * H + 255) / 256, 256, 0, stream>>>(Wn2, Wn2t, H);
    wtrans_kernel<<<(384 * H + 255) / 256, 256, 0, stream>>>(We1, We1t, 384);
    wtrans_kernel<<<(H * H + 255) / 256, 256, 0, stream>>>(We2, We2t, H);

    hipMemsetAsync(cnt, 0, (size_t)N * sizeof(int), stream);
    hist_kernel<<<(E + 255) / 256, 256, 0, stream>>>(ei, cnt, E);
    scan_kernel<<<1, 1024, 0, stream>>>(cnt, off, N);
    hipMemcpyAsync(cursor, off, (size_t)N * sizeof(int),
                   hipMemcpyDeviceToDevice, stream);
    reorder_kernel<<<(E + 255) / 256, 256, 0, stream>>>(ei, cursor, sorted, E);
    segsum_kernel<<<(N + 3) / 4, 256, 0, stream>>>(e, sorted, off, msgs, N);

    {
        int blocks = (N + 63) / 64;
        node_mlp_kernel<<<blocks, 256, 0, stream>>>(
            x, msgs, Wn1t, bn1, gn1, betan1, Wn2t, bn2, x_out, xbf, N);
    }
    {
        int blocks = (E + 63) / 64;
        edge_mlp_kernel<<<blocks, 256, 0, stream>>>(
            xbf, e, ei, We1t, be1, ge1, betae1, We2t, be2, e_out, E);
    }
}